// Round 6
// baseline (260.911 us; speedup 1.0000x reference)
//
#include <hip/hip_runtime.h>

// Problem constants (fixed by the reference setup)
#define NEDGE  500000
#define GS2_N  20000      // destination graph nodes (SIZE2/4)
#define SIZE1  80000
#define SIZE2  80000
#define BATCH  8
#define CAP    64         // bucket capacity per dst node (max Poisson(25) degree ~55)

// ---------------------------------------------------------------------------
// K1 (build): per edge read rows[e*16] (dst*4) and cols[e*16] (src*4); one int
// atomic on the 80 KB histogram; store an 8 B record {e, s4} into bucket slot
// d*CAP+pos. No weight traffic here — the permutation alone crosses the
// edge-order -> dst-order boundary. Also kl=0.
__global__ void build_kernel(const int* __restrict__ rows,
                             const int* __restrict__ cols,
                             int* __restrict__ counts,
                             int2* __restrict__ recs,
                             float* __restrict__ out) {
    int e = blockIdx.x * blockDim.x + threadIdx.x;
    if (e == 0) out[(long)BATCH * SIZE2] = 0.0f;   // kl output
    if (e >= NEDGE) return;
    long base = (long)e << 4;
    int d  = rows[base] >> 2;                      // dst node id
    int s4 = cols[base];                           // src*4
    int pos = atomicAdd(counts + d, 1);
    if (pos < CAP)                                 // defensive clamp (P(overflow)~1e-7)
        recs[(long)d * CAP + pos] = make_int2(e, s4);
}

// ---------------------------------------------------------------------------
// K2 (gather): one wave per dst node; lane = (s = lane>>3 edge-slot, b = lane&7
// batch). Per record: load the edge's 3x64 B weight chunks directly (the 8
// b-lanes share addresses -> coalesced to one fetch), v = ew*exp(wlv)+wm,
// dot with x[b, src*4..+3]; butterfly-reduce over s; lanes s==0 store float4
// with fused reparameterized bias.
__global__ __launch_bounds__(256) void gather_kernel(
        const float* __restrict__ x,
        const float* __restrict__ wm,
        const float* __restrict__ wlv,
        const float* __restrict__ ew,
        const int2* __restrict__ recs,
        const int* __restrict__ counts,
        const float* __restrict__ b_mean,
        const float* __restrict__ b_lv,
        const float* __restrict__ eps_b,
        float* __restrict__ out) {
    int wave = threadIdx.x >> 6;
    int lane = threadIdx.x & 63;
    int n = blockIdx.x * 4 + wave;          // dst node
    if (n >= GS2_N) return;
    int s = lane >> 3;                       // edge slot 0..7
    int b = lane & 7;                        // batch 0..7
    int cnt = counts[n]; if (cnt > CAP) cnt = CAP;
    long rbase = (long)n * CAP;

    float a0 = 0.f, a1 = 0.f, a2 = 0.f, a3 = 0.f;
    for (int p = s; p < cnt; p += 8) {
        int2 rec = recs[rbase + p];
        long base = (long)rec.x << 4;
        float4 xb = *(const float4*)(x + (long)b * SIZE1 + rec.y);
        float xi[4] = { xb.x, xb.y, xb.z, xb.w };
#pragma unroll
        for (int i = 0; i < 4; ++i) {
            float4 m = *(const float4*)(wm  + base + i * 4);
            float4 l = *(const float4*)(wlv + base + i * 4);
            float4 w = *(const float4*)(ew  + base + i * 4);
            float v0 = w.x * __expf(l.x) + m.x;
            float v1 = w.y * __expf(l.y) + m.y;
            float v2 = w.z * __expf(l.z) + m.z;
            float v3 = w.w * __expf(l.w) + m.w;
            a0 += v0 * xi[i];
            a1 += v1 * xi[i];
            a2 += v2 * xi[i];
            a3 += v3 * xi[i];
        }
    }
#pragma unroll
    for (int mask = 8; mask <= 32; mask <<= 1) {
        a0 += __shfl_xor(a0, mask, 64);
        a1 += __shfl_xor(a1, mask, 64);
        a2 += __shfl_xor(a2, mask, 64);
        a3 += __shfl_xor(a3, mask, 64);
    }
    if (s == 0) {
        int r = n * 4;
        float4 bm  = *(const float4*)(b_mean + r);
        float4 blv = *(const float4*)(b_lv + r);
        float4 eb  = *(const float4*)(eps_b + r);
        float4 o;
        o.x = a0 + eb.x * __expf(blv.x) + bm.x;
        o.y = a1 + eb.y * __expf(blv.y) + bm.y;
        o.z = a2 + eb.z * __expf(blv.z) + bm.z;
        o.w = a3 + eb.w * __expf(blv.w) + bm.w;
        *(float4*)(out + (long)b * SIZE2 + r) = o;
    }
}

// ---------------------------------------------------------------------------
extern "C" void kernel_launch(void* const* d_in, const int* in_sizes, int n_in,
                              void* d_out, int out_size, void* d_ws, size_t ws_size,
                              hipStream_t stream) {
    const float* x      = (const float*)d_in[0];
    const float* wm     = (const float*)d_in[1];
    const float* wlv    = (const float*)d_in[2];
    const float* b_mean = (const float*)d_in[3];
    const float* b_lv   = (const float*)d_in[4];
    const float* ew     = (const float*)d_in[5];
    const float* eps_b  = (const float*)d_in[6];
    const int*   rows   = (const int*)d_in[7];
    const int*   cols   = (const int*)d_in[8];
    float* out = (float*)d_out;

    (void)in_sizes; (void)n_in; (void)out_size; (void)ws_size;

    // Workspace layout:
    //   recs   : int2[GS2_N * CAP] = 10.24 MB (8 B records, bucketed by dst)
    //   counts : int[GS2_N]        = 80 KB
    int2* recs  = (int2*)d_ws;
    int* counts = (int*)(recs + (long)GS2_N * CAP);

    hipMemsetAsync(counts, 0, GS2_N * sizeof(int), stream);

    int block = 256;
    int egrid = (NEDGE + block - 1) / block;
    build_kernel<<<egrid, block, 0, stream>>>(rows, cols, counts, recs, out);
    gather_kernel<<<GS2_N / 4, 256, 0, stream>>>(x, wm, wlv, ew, recs, counts,
                                                 b_mean, b_lv, eps_b, out);
}